// Round 15
// baseline (109.451 us; speedup 1.0000x reference)
//
#include <hip/hip_runtime.h>
#include <hip/hip_bf16.h>

// VectorQuantizer: x [32768 x 64] fp32, e [64 x 1024] fp32.
// d_out = [out (2097152 f32) = x + (q-x), loss = 1.25*mean((q-x)^2)].
//
// R15 = R14 (LDS-resident fp16 codebook scan, validated absmax-0) with vq_fix
// FUSED into vq_main: flagged rows (gap < MARGIN) are exactly re-scored
// in-block BEFORE the epilogue (512-thread parallel recheck, R1-bit-exact
// ascending-fmaf chains over eT + sse), so rowIdx is corrected first and no
// out/loss patching or third dispatch is needed. Loss = parts[256] summed by
// main's atomic-ticket last block. 2 dispatches (was 3) — attacks the
// ~15-20us/node overhead visible in R4-vs-R9 ledger arithmetic.
// Safe vs R5's inlining disaster: scan live set is ~55 regs (LDS codebook,
// no register B-ring), recheck is phase-sequential with ~30 regs, and the
// 132KB LDS already caps occupancy at 1 block/CU (no allocator incentive).

#define NROWS 32768
#define DDIM  64
#define KCODE 1024
#define NELEM (NROWS * DDIM)
#define MARGIN 4e-3f
#define MAINBLK 256          // 1 block/CU, 512 threads, 128 rows/block

typedef __attribute__((ext_vector_type(8))) _Float16 f16x8;
typedef __attribute__((ext_vector_type(4))) float f32x4;

static __device__ __forceinline__ unsigned short f2h(float v) {
    _Float16 h = (_Float16)v;
    unsigned short b;
    __builtin_memcpy(&b, &h, 2);
    return b;
}
static __device__ __forceinline__ void gload16(const void* g, void* l) {
    __builtin_amdgcn_global_load_lds(
        (const __attribute__((address_space(1))) void*)g,
        (__attribute__((address_space(3))) void*)l, 16, 0, 0);
}

// ---------------------------------------------------------------------------
// prep (64 blocks x 256): per block 16 codes. se[k] exact fp32 (ascending-d
// fmaf — must match recheck), eT[k][d] fp32, ehSw[k][*] fp16 with the
// 16B-chunk XOR swizzle (chunk ch of code k at slot ch^(k&7)) so the LDS
// image (bit-copied by global_load_lds) serves conflict-free ds_read_b128.
__global__ void vq_prep(const float* __restrict__ e,
                        float* __restrict__ se,
                        float* __restrict__ eT,
                        unsigned short* __restrict__ ehSw,
                        int* __restrict__ ctrl) {
    __shared__ float tile[64][17];
    const int t = threadIdx.x;
    const int k0 = blockIdx.x * 16;
    if (blockIdx.x == 0 && t < 4) ctrl[t] = 0;
    #pragma unroll
    for (int i = 0; i < 4; ++i) {
        int idx = i * 256 + t;
        int d = idx >> 4, kk = idx & 15;
        tile[d][kk] = e[d * KCODE + k0 + kk];
    }
    __syncthreads();
    if (t < 16) {
        float s = 0.f;
        #pragma unroll
        for (int d = 0; d < 64; ++d) { float v = tile[d][t]; s = fmaf(v, v, s); }
        se[k0 + t] = s;
    }
    const int kk = t >> 4;            // code 0..15 within block
    const int dg = (t & 15) * 4;      // dim group (4 elems)
    const int kg = k0 + kk;
    float v0 = tile[dg + 0][kk], v1 = tile[dg + 1][kk];
    float v2 = tile[dg + 2][kk], v3 = tile[dg + 3][kk];
    *(float4*)&eT[(size_t)kg * 64 + dg] = make_float4(v0, v1, v2, v3);
    const int sw = (((dg >> 3) ^ (kg & 7)) << 3) + (dg & 7);
    *(ushort4*)&ehSw[(size_t)kg * 64 + sw] =
        make_ushort4(f2h(v0), f2h(v1), f2h(v2), f2h(v3));
}

// ---------------------------------------------------------------------------
__launch_bounds__(512)
__global__ void vq_main(const float* __restrict__ x,
                        const float* __restrict__ se,
                        const float* __restrict__ eT,
                        const unsigned short* __restrict__ ehSw,
                        float* __restrict__ out,
                        float* __restrict__ parts,
                        int* __restrict__ done) {
    __shared__ unsigned short Beh[KCODE * 64];   // 128 KB, swizzled fp16 codebook
    __shared__ float sse[KCODE];                 // 4 KB (bit-copy of se)
    __shared__ float cbuf[512];                  // recheck / final reduce
    __shared__ int   cibuf[512];
    __shared__ int   rowIdx[128];
    __shared__ int   flagRows[128];
    __shared__ int   nFlag;
    __shared__ float xs[64];
    __shared__ float wsum[8];
    __shared__ int   lastS;

    const int t = threadIdx.x;          // 0..511
    const int lane = t & 63;
    const int w = t >> 6;               // wave 0..7
    const int quad = lane >> 4, l15 = lane & 15;
    const int rowBlk = blockIdx.x * 128;
    const int rowBase = rowBlk + w * 16;   // wave owns 16 rows

    if (t == 0) { nFlag = 0; lastS = 0; }

    // ---- stage codebook (bit-copy of the swizzled global image) + se ----
    {
        const unsigned char* g = (const unsigned char*)ehSw;
        #pragma unroll
        for (int r = 0; r < 16; ++r)
            gload16(g + (size_t)(r * 512 + t) * 16, &Beh[(r * 512 + t) * 8]);
        float2 s2 = ((const float2*)se)[t];
        sse[2 * t + 0] = s2.x;
        sse[2 * t + 1] = s2.y;
    }

    // ---- A fragments (fp16 two-term split): row = l15, k = quad*8+ks*32+j ----
    f16x8 ah0, ah1, al0, al1;
    {
        const float4* ap0 = (const float4*)(x + (size_t)(rowBase + l15) * 64 + quad * 8);
        const float4* ap1 = (const float4*)(x + (size_t)(rowBase + l15) * 64 + 32 + quad * 8);
        float4 a0 = ap0[0], a1 = ap0[1], b0 = ap1[0], b1 = ap1[1];
        float av[8] = {a0.x, a0.y, a0.z, a0.w, a1.x, a1.y, a1.z, a1.w};
        float bv[8] = {b0.x, b0.y, b0.z, b0.w, b1.x, b1.y, b1.z, b1.w};
        f16x8 h0, h1, l0, l1;
        #pragma unroll
        for (int j = 0; j < 8; ++j) {
            _Float16 ha = (_Float16)av[j];
            _Float16 hb = (_Float16)bv[j];
            h0[j] = ha;
            h1[j] = hb;
            l0[j] = (_Float16)(av[j] - (float)ha);
            l1[j] = (_Float16)(bv[j] - (float)hb);
        }
        ah0 = h0; ah1 = h1; al0 = l0; al1 = l1;
    }
    __syncthreads();   // codebook + se resident; drains gload16 vmcnt

    // ---- barrier-free scan: 64 iters x 16 codes, all from LDS ----
    float sb[4], sb2[4];
    int   si[4];
    #pragma unroll
    for (int r = 0; r < 4; ++r) { sb[r] = 3.4e38f; sb2[r] = 3.4e38f; si[r] = 0; }

    const int slot0 = ((quad ^ (l15 & 7)) << 3);        // ks=0 chunk (elems)
    const int slot1 = (((quad + 4) ^ (l15 & 7)) << 3);  // ks=1 chunk

    #pragma unroll 4
    for (int nt = 0; nt < 64; ++nt) {
        const int code = nt * 16 + l15;
        f16x8 b0 = *(const f16x8*)&Beh[code * 64 + slot0];
        f16x8 b1 = *(const f16x8*)&Beh[code * 64 + slot1];
        float cse = sse[code];
        f32x4 aA = {0.f, 0.f, 0.f, 0.f}, aB = {0.f, 0.f, 0.f, 0.f};
        aA = __builtin_amdgcn_mfma_f32_16x16x32_f16(ah0, b0, aA, 0, 0, 0);
        aB = __builtin_amdgcn_mfma_f32_16x16x32_f16(ah1, b1, aB, 0, 0, 0);
        aA = __builtin_amdgcn_mfma_f32_16x16x32_f16(al0, b0, aA, 0, 0, 0);
        aB = __builtin_amdgcn_mfma_f32_16x16x32_f16(al1, b1, aB, 0, 0, 0);
        #pragma unroll
        for (int r = 0; r < 4; ++r) {
            float key = fmaf(-2.f, aA[r] + aB[r], cse);   // ~ se - 2*x·e
            bool lt = key < sb[r];                 // strict: earliest code wins
            sb2[r] = fminf(sb2[r], fmaxf(sb[r], key));
            sb[r]  = fminf(sb[r], key);
            si[r]  = lt ? code : si[r];
        }
    }

    // ---- in-wave butterfly argmin over the 16 lanes of each quad ----
    #pragma unroll
    for (int m = 1; m < 16; m <<= 1) {
        #pragma unroll
        for (int r = 0; r < 4; ++r) {
            float ob  = __shfl_xor(sb[r],  m, 64);
            float ob2 = __shfl_xor(sb2[r], m, 64);
            int   oi  = __shfl_xor(si[r],  m, 64);
            float nb2 = fminf(fminf(sb2[r], ob2), fmaxf(sb[r], ob));
            bool take = (ob < sb[r]) || (ob == sb[r] && oi < si[r]);
            sb[r] = take ? ob : sb[r];
            si[r] = take ? oi : si[r];
            sb2[r] = nb2;
        }
    }

    // ---- publish per-row idx; flag ambiguous rows for in-block recheck ----
    if (l15 == 0) {
        #pragma unroll
        for (int r = 0; r < 4; ++r) {
            const int rl = w * 16 + quad * 4 + r;     // block-local row
            rowIdx[rl] = si[r];
            if (sb2[r] - sb[r] < MARGIN) {
                int p = atomicAdd(&nFlag, 1);
                flagRows[p] = rl;
            }
        }
    }
    __syncthreads();

    // ---- exact fp32 recheck of flagged rows (rare; R1-bit-exact math) ----
    {
        const int nf = nFlag;
        for (int f = 0; f < nf; ++f) {
            const int r = flagRows[f];
            if (t < 64) xs[t] = x[(size_t)(rowBlk + r) * 64 + t];
            __syncthreads();

            float sx = 0.f;
            #pragma unroll
            for (int d = 0; d < 64; ++d) sx = fmaf(xs[d], xs[d], sx);

            // thread t owns codes 2t, 2t+1 — two interleaved independent
            // chains, each ascending-d (bit-identical to validated math)
            const int k0 = t * 2;
            const float4* e0 = (const float4*)(eT + (size_t)(k0 + 0) * 64);
            const float4* e1 = (const float4*)(eT + (size_t)(k0 + 1) * 64);
            float dot0 = 0.f, dot1 = 0.f;
            #pragma unroll
            for (int i4 = 0; i4 < 16; ++i4) {
                float4 v0 = e0[i4], v1 = e1[i4];
                float xa = xs[4 * i4 + 0], xb = xs[4 * i4 + 1];
                float xc = xs[4 * i4 + 2], xd = xs[4 * i4 + 3];
                dot0 = fmaf(xa, v0.x, dot0); dot0 = fmaf(xb, v0.y, dot0);
                dot0 = fmaf(xc, v0.z, dot0); dot0 = fmaf(xd, v0.w, dot0);
                dot1 = fmaf(xa, v1.x, dot1); dot1 = fmaf(xb, v1.y, dot1);
                dot1 = fmaf(xc, v1.z, dot1); dot1 = fmaf(xd, v1.w, dot1);
            }
            float dd0 = (sx + sse[k0 + 0]) - 2.0f * dot0;
            float dd1 = (sx + sse[k0 + 1]) - 2.0f * dot1;
            float db = dd0; int di = k0;
            if (dd1 < db) { db = dd1; di = k0 + 1; }
            cbuf[t] = db; cibuf[t] = di;
            __syncthreads();

            if (t < 64) {   // parallel reduce: 512 -> 64 fold + butterfly
                float B = cbuf[t]; int I = cibuf[t];
                #pragma unroll
                for (int s = 64; s < 512; s += 64) {
                    float b = cbuf[t + s]; int i2 = cibuf[t + s];
                    bool take = (b < B) || (b == B && i2 < I);
                    B = take ? b : B;
                    I = take ? i2 : I;
                }
                #pragma unroll
                for (int m = 1; m < 64; m <<= 1) {
                    float ob = __shfl_xor(B, m, 64);
                    int   oi = __shfl_xor(I, m, 64);
                    bool take = (ob < B) || (ob == B && oi < I);
                    B = take ? ob : B;
                    I = take ? oi : I;
                }
                if (t == 0) rowIdx[r] = I;
            }
            __syncthreads();
        }
    }

    // ---- epilogue: lane -> row rowBase+l15, elems [quad*16, quad*16+16) ----
    {
        const int idx = rowIdx[w * 16 + l15];
        const float4* qrow = (const float4*)(eT + (size_t)idx * 64 + quad * 16);
        const float4* xrow = (const float4*)(x + (size_t)(rowBase + l15) * 64 + quad * 16);
        float4* orow = (float4*)(out + (size_t)(rowBase + l15) * 64 + quad * 16);
        float lsum = 0.f;
        #pragma unroll
        for (int i = 0; i < 4; ++i) {
            float4 q = qrow[i];
            float4 xv = xrow[i];
            float4 o;
            float dx;
            dx = q.x - xv.x; o.x = xv.x + dx; lsum = fmaf(dx, dx, lsum);
            dx = q.y - xv.y; o.y = xv.y + dx; lsum = fmaf(dx, dx, lsum);
            dx = q.z - xv.z; o.z = xv.z + dx; lsum = fmaf(dx, dx, lsum);
            dx = q.w - xv.w; o.w = xv.w + dx; lsum = fmaf(dx, dx, lsum);
            orow[i] = o;
        }
        #pragma unroll
        for (int off = 32; off > 0; off >>= 1)
            lsum += __shfl_down(lsum, off, 64);
        if (lane == 0) wsum[w] = lsum;
    }
    __syncthreads();

    // ---- block partial -> parts[]; ticket-last block finalizes the loss ----
    if (t == 0) {
        float s = 0.f;
        #pragma unroll
        for (int i = 0; i < 8; ++i) s += wsum[i];
        parts[blockIdx.x] = s;
        __threadfence();
        int fin = atomicAdd(done, 1);
        if (fin == MAINBLK - 1) lastS = 1;
    }
    __syncthreads();
    if (lastS) {
        if (t < 256) cbuf[t] = parts[t];
        __syncthreads();
        if (t < 64) {
            float v = cbuf[t] + cbuf[t + 64] + cbuf[t + 128] + cbuf[t + 192];
            #pragma unroll
            for (int off = 32; off > 0; off >>= 1)
                v += __shfl_down(v, off, 64);
            if (t == 0) {
                float m = v / (float)NELEM;
                out[NELEM] = 0.25f * m + m;
            }
        }
    }
}

// ---------------------------------------------------------------------------
extern "C" void kernel_launch(void* const* d_in, const int* in_sizes, int n_in,
                              void* d_out, int out_size, void* d_ws, size_t ws_size,
                              hipStream_t stream) {
    const float* x = (const float*)d_in[0];
    const float* e = (const float*)d_in[1];
    float* out = (float*)d_out;
    float* ws  = (float*)d_ws;

    // ws layout (float offsets):
    //   [0..15]   ctrl: (unused), (unused), done, spare
    //   +64       se   [1024]
    //   +1280     eT   [65536]
    //   +66816    ehSw [65536 ushort = 32768 f]  (swizzled fp16, LDS image)
    //   +99584    parts[256]
    int*   done          = (int*)(ws + 2);
    float* se            = ws + 64;
    float* eT            = ws + 1280;
    unsigned short* ehSw = (unsigned short*)(ws + 66816);
    float* parts         = ws + 99584;

    vq_prep<<<64, 256, 0, stream>>>(e, se, eT, ehSw, (int*)ws);
    vq_main<<<MAINBLK, 512, 0, stream>>>(x, se, eT, ehSw, out, parts, done);
}